// Round 2
// baseline (447.365 us; speedup 1.0000x reference)
//
#include <hip/hip_runtime.h>
#include <hip/hip_bf16.h>

// Problem constants (fixed by reference setup_inputs)
constexpr int Bn = 128;   // batch
constexpr int Tn = 32;    // timesteps
constexpr int Dn = 6400;  // input dim (K)
constexpr int Hn = 1000;  // hidden  (N)
constexpr int An = 4;     // actions
constexpr int Mn = Bn * Tn;   // 4096 GEMM rows
constexpr int Npad = 1024;    // W rows padded -> no N-guards in GEMM

constexpr int KS = Dn / 32;   // 200 k-chunks of 32
constexpr int MC = Mn / 16;   // 256 m-chunks of 16 rows
constexpr int NC = Npad / 16; // 64  n-chunks of 16 rows

typedef _Float16 half8 __attribute__((ext_vector_type(8)));
typedef _Float16 half4 __attribute__((ext_vector_type(4)));
typedef float floatx4 __attribute__((ext_vector_type(4)));

// Workspace layouts (bytes)
constexpr size_t H1_BYTES  = (size_t)Mn * Hn * 4;       // 16,384,000
constexpr size_t XS_BYTES  = (size_t)Mn * Dn * 2;       // per split
constexpr size_t WSp_BYTES = (size_t)Npad * Dn * 2;     // per split
constexpr size_t WS_R7     = H1_BYTES + 2 * XS_BYTES + 2 * WSp_BYTES;      // 147,456,000
constexpr size_t WS_SPLITK = 2 * H1_BYTES + 2 * XS_BYTES + 2 * WSp_BYTES;  // 163,840,000

__device__ __forceinline__ void async16(const void* g, void* l) {
    __builtin_amdgcn_global_load_lds(
        (const __attribute__((address_space(1))) void*)g,
        (__attribute__((address_space(3))) void*)l, 16, 0, 0);
}

// ---------------------------------------------------------------------------
// Pre-pass (r7/r8-verified): fp16 hi/lo split into fragment-chunk layout,
// both sides 1KB-per-instruction coalesced via LDS transpose.
// ---------------------------------------------------------------------------
__global__ __launch_bounds__(256)
void cvt2(const float* __restrict__ X, const float* __restrict__ W1,
          _Float16* __restrict__ Xh, _Float16* __restrict__ Xl,
          _Float16* __restrict__ Wh, _Float16* __restrict__ Wl)
{
    constexpr int LD2 = 264;
    __shared__ __align__(16) _Float16 hiS[16][LD2];
    __shared__ __align__(16) _Float16 loS[16][LD2];

    const int tid = threadIdx.x;
    const int lane = tid & 63;
    const int w = tid >> 6;
    const int bx = blockIdx.x;

    const float* src;
    _Float16 *dh, *dl;
    int c4, ks0, crow, nrows;
    if (bx < 256 * 25) {                       // X part
        c4 = bx & 255; ks0 = (bx >> 8) * 8;
        src = X; dh = Xh; dl = Xl; crow = MC; nrows = 16;
    } else {                                   // W part (rows >= Hn zeroed)
        const int b2 = bx - 256 * 25;
        c4 = b2 & 63; ks0 = (b2 >> 6) * 8;
        src = W1; dh = Wh; dl = Wl; crow = NC; nrows = Hn - c4 * 16;
    }

#pragma unroll
    for (int j = 0; j < 4; ++j) {
        const int row = w * 4 + j;
        float4 v = make_float4(0.f, 0.f, 0.f, 0.f);
        if (row < nrows)
            v = *(const float4*)(src + (size_t)(c4 * 16 + row) * Dn + ks0 * 32 + lane * 4);
        half4 hi, lo;
        hi[0] = (_Float16)v.x; lo[0] = (_Float16)((v.x - (float)hi[0]) * 4096.0f);
        hi[1] = (_Float16)v.y; lo[1] = (_Float16)((v.y - (float)hi[1]) * 4096.0f);
        hi[2] = (_Float16)v.z; lo[2] = (_Float16)((v.z - (float)hi[2]) * 4096.0f);
        hi[3] = (_Float16)v.w; lo[3] = (_Float16)((v.w - (float)hi[3]) * 4096.0f);
        *(half4*)&hiS[row][lane * 4] = hi;
        *(half4*)&loS[row][lane * 4] = lo;
    }
    __syncthreads();

    const int lr = lane & 15, lg = lane >> 4;
#pragma unroll
    for (int q = 0; q < 2; ++q) {
        const int ks = w * 2 + q;
        const size_t cbase = ((size_t)(ks0 + ks) * crow + c4) * 512;
        const half8 h = *(const half8*)&hiS[lr][ks * 32 + lg * 8];
        const half8 l = *(const half8*)&loS[lr][ks * 32 + lg * 8];
        *(half8*)(dh + cbase + lane * 8) = h;
        *(half8*)(dl + cbase + lane * 8) = l;
    }
}

// ---------------------------------------------------------------------------
// GEMM (primary): 128x128 tile, split-K=2, A via LDS-DMA / B direct-to-reg.
//
// r10 change (T3/T4 counted-vmcnt): r8/r9 both sat at MfmaUtil ~50% because
// __syncthreads() compiles to "s_waitcnt vmcnt(0) lgkmcnt(0); s_barrier" --
// a full vmem drain every k-iter (~1000 idle cyc/iter of the 3504 measured).
// Replace with: 4-buffer LDS rotation (64 KB), A-DMA issued 2 iters ahead,
// raw s_barrier preceded by "s_waitcnt vmcnt(12)".  At barrier(it) the
// outstanding vmem set is exactly {DMA(it+1):4, B(it):8} = 12 ops; everything
// older (incl. DMA(it), the buffer about to be read) has retired in-order
// because B(it-1), issued after DMA(it), was register-waited by MFMA(it-1).
// So prefetched loads stay in flight ACROSS barriers (never drained to 0).
// Buffer-overwrite safety: DMA(it+2) hits buf((it+2)&3), last read in iter
// it-2, whose ds_reads completed before barrier(it-1).
// 4-deep rotation => all buf/B-set indices are compile-time (NIT=100=4*25).
// LDS 64 KB x 2 blocks = 128 <= 160 KB; regs ~120 VGPR + 128 AGPR <= 256
// => 2 blocks/CU preserved.
// ---------------------------------------------------------------------------
__global__ __launch_bounds__(256, 2)
void gemm_sk2(const _Float16* __restrict__ Xh, const _Float16* __restrict__ Xl,
              const _Float16* __restrict__ Wh, const _Float16* __restrict__ Wl,
              float* __restrict__ H1)
{
    __shared__ __align__(16) _Float16 S[4][16][512];   // 64 KB: [buf][A chunk hi0-7,lo0-7][1KB]

    const int tid = threadIdx.x;
    const int lane = tid & 63;
    const int w = tid >> 6;
    const int kh = blockIdx.x & 1;
    const int nb = (blockIdx.x >> 1) & 7;
    const int mb = blockIdx.x >> 4;
    const int bm8 = mb * 8;
    const int bn8 = nb * 8;
    const int wm = w & 1;
    const int wn = w >> 1;
    const int ks0 = kh * (KS / 2);
    constexpr int NIT = KS / 2;                // 100 = 4*25

    // A staging: wave w stages hi+lo of m-chunks 2w, 2w+1 (4 async16/wave).
    auto issueA = [&](int ks, int buf) {
        _Float16* base = &S[buf][0][0];
#pragma unroll
        for (int r = 0; r < 2; ++r) {
            const int i = w * 2 + r;
            const size_t ga = ((size_t)(ks * MC + bm8 + i)) * 512 + lane * 8;
            async16(Xh + ga, base + (0 + i) * 512);
            async16(Xl + ga, base + (8 + i) * 512);
        }
    };

    // B fragments: direct global->VGPR, lane-contiguous 1 KB per instruction.
    const _Float16* bhp = Wh + ((size_t)(ks0 * NC + bn8 + wn * 4)) * 512 + lane * 8;
    const _Float16* blp = Wl + ((size_t)(ks0 * NC + bn8 + wn * 4)) * 512 + lane * 8;
    constexpr size_t BSTEP = (size_t)NC * 512;         // per-ks advance (halves)

    floatx4 acc0[4][4] = {};
    floatx4 acc1[4][4] = {};

    half8 bh0[4], bl0[4], bh1[4], bl1[4];              // B reg double-buffer

    // prologue: A-DMA for it=0,1 into buf0,1; B(0) into set0
    issueA(ks0 + 0, 0);
    issueA(ks0 + 1, 1);
#pragma unroll
    for (int nt = 0; nt < 4; ++nt) {
        bh0[nt] = *(const half8*)(bhp + nt * 512);
        bl0[nt] = *(const half8*)(blp + nt * 512);
    }

    // Body(IT): [vmcnt(12); s_barrier] ; DMA(IT+2)->buf((IT+2)&3) ;
    //           loadB(IT+1)->BN ; MFMA(IT) on S[BUF] x BC.
#define SK2_BODY(IT, BUF, BHC, BLC, BHN, BLN)                                   \
    {                                                                           \
        asm volatile("s_waitcnt vmcnt(12)" ::: "memory");                       \
        __builtin_amdgcn_sched_barrier(0);                                      \
        __builtin_amdgcn_s_barrier();                                           \
        __builtin_amdgcn_sched_barrier(0);                                      \
        if ((IT) + 2 < NIT) issueA(ks0 + (IT) + 2, ((IT) + 2) & 3);             \
        if ((IT) + 1 < NIT) {                                                   \
            const size_t bo = (size_t)((IT) + 1) * BSTEP;                       \
            _Pragma("unroll")                                                   \
            for (int nt = 0; nt < 4; ++nt) {                                    \
                BHN[nt] = *(const half8*)(bhp + bo + nt * 512);                 \
                BLN[nt] = *(const half8*)(blp + bo + nt * 512);                 \
            }                                                                   \
        }                                                                       \
        _Pragma("unroll")                                                       \
        for (int mt = 0; mt < 4; ++mt) {                                        \
            const half8 ah = *(const half8*)&S[BUF][wm * 4 + mt][lane * 8];     \
            const half8 al = *(const half8*)&S[BUF][8 + wm * 4 + mt][lane * 8]; \
            _Pragma("unroll")                                                   \
            for (int nt = 0; nt < 4; ++nt) {                                    \
                acc0[mt][nt] = __builtin_amdgcn_mfma_f32_16x16x32_f16(ah, BHC[nt], acc0[mt][nt], 0, 0, 0); \
                acc1[mt][nt] = __builtin_amdgcn_mfma_f32_16x16x32_f16(ah, BLC[nt], acc1[mt][nt], 0, 0, 0); \
                acc1[mt][nt] = __builtin_amdgcn_mfma_f32_16x16x32_f16(al, BHC[nt], acc1[mt][nt], 0, 0, 0); \
            }                                                                   \
        }                                                                       \
    }

    for (int it = 0; it < NIT; it += 4) {
        SK2_BODY(it + 0, 0, bh0, bl0, bh1, bl1);
        SK2_BODY(it + 1, 1, bh1, bl1, bh0, bl0);
        SK2_BODY(it + 2, 2, bh0, bl0, bh1, bl1);
        SK2_BODY(it + 3, 3, bh1, bl1, bh0, bl0);
    }
#undef SK2_BODY

    // epilogue (no bias -- scan adds b1): C/D col=lane&15, row=(lane>>4)*4+r
    float* H1o = H1 + (size_t)kh * ((size_t)Mn * Hn);
    const int fr = lane & 15;
    const int fq = lane >> 4;
#pragma unroll
    for (int nt = 0; nt < 4; ++nt) {
        const int n = nb * 128 + wn * 64 + nt * 16 + fr;
        if (n >= Hn) continue;
#pragma unroll
        for (int mt = 0; mt < 4; ++mt) {
            const int m = mb * 128 + wm * 64 + mt * 16 + fq * 4;
#pragma unroll
            for (int r = 0; r < 4; ++r)
                H1o[(size_t)(m + r) * Hn + n] =
                    acc0[mt][nt][r] + acc1[mt][nt][r] * (1.0f / 4096.0f);
        }
    }
}

// ---------------------------------------------------------------------------
// GEMM mid-fallback (r7-verified; bias removed): ws in [147,164) MB.
// ---------------------------------------------------------------------------
constexpr int AH = 0;
constexpr int AL = 8 * 512;
constexpr int BH = 16 * 512;
constexpr int BL = 20 * 512;
constexpr int BUFSZ = 24 * 512;

__global__ __launch_bounds__(256, 2)
void gemm_frag2(const _Float16* __restrict__ Xh, const _Float16* __restrict__ Xl,
                const _Float16* __restrict__ Wh, const _Float16* __restrict__ Wl,
                float* __restrict__ H1)
{
    __shared__ __align__(16) _Float16 S[2 * BUFSZ];

    const int tid = threadIdx.x;
    const int lane = tid & 63;
    const int w = tid >> 6;
    const int nb = blockIdx.x & 15;
    const int mb = blockIdx.x >> 4;
    const int bm4 = mb * 8;
    const int bn4 = nb * 4;
    const int wm = w & 1;
    const int wn = w >> 1;

    auto issue = [&](int ks, int buf) {
        _Float16* base = &S[buf * BUFSZ];
#pragma unroll
        for (int r = 0; r < 2; ++r) {
            const int i = w * 2 + r;
            const size_t ga = ((size_t)(ks * MC + bm4 + i)) * 512 + lane * 8;
            async16(Xh + ga, base + AH + i * 512);
            async16(Xl + ga, base + AL + i * 512);
        }
        const size_t gb = ((size_t)(ks * NC + bn4 + w)) * 512 + lane * 8;
        async16(Wh + gb, base + BH + w * 512);
        async16(Wl + gb, base + BL + w * 512);
    };

    floatx4 acc0[4][2] = {};
    floatx4 acc1[4][2] = {};

    issue(0, 0);
    for (int it = 0; it < KS; ++it) {
        const int buf = it & 1;
        __syncthreads();
        if (it + 1 < KS) issue(it + 1, buf ^ 1);

        const _Float16* base = &S[buf * BUFSZ];
        half8 ah[4], al[4], bh[2], bl[2];
#pragma unroll
        for (int mt = 0; mt < 4; ++mt) {
            ah[mt] = *(const half8*)(base + AH + (wm * 4 + mt) * 512 + lane * 8);
            al[mt] = *(const half8*)(base + AL + (wm * 4 + mt) * 512 + lane * 8);
        }
#pragma unroll
        for (int nt = 0; nt < 2; ++nt) {
            bh[nt] = *(const half8*)(base + BH + (wn * 2 + nt) * 512 + lane * 8);
            bl[nt] = *(const half8*)(base + BL + (wn * 2 + nt) * 512 + lane * 8);
        }
#pragma unroll
        for (int mt = 0; mt < 4; ++mt)
#pragma unroll
            for (int nt = 0; nt < 2; ++nt) {
                acc0[mt][nt] = __builtin_amdgcn_mfma_f32_16x16x32_f16(ah[mt], bh[nt], acc0[mt][nt], 0, 0, 0);
                acc1[mt][nt] = __builtin_amdgcn_mfma_f32_16x16x32_f16(ah[mt], bl[nt], acc1[mt][nt], 0, 0, 0);
                acc1[mt][nt] = __builtin_amdgcn_mfma_f32_16x16x32_f16(al[mt], bh[nt], acc1[mt][nt], 0, 0, 0);
            }
    }

    const int fr = lane & 15;
    const int fq = lane >> 4;
#pragma unroll
    for (int nt = 0; nt < 2; ++nt) {
        const int n = nb * 64 + wn * 32 + nt * 16 + fr;
        if (n >= Hn) continue;
#pragma unroll
        for (int mt = 0; mt < 4; ++mt) {
            const int m = mb * 128 + wm * 64 + mt * 16 + fq * 4;
#pragma unroll
            for (int r = 0; r < 4; ++r)
                H1[(size_t)(m + r) * Hn + n] =
                    acc0[mt][nt][r] + acc1[mt][nt][r] * (1.0f / 4096.0f);
        }
    }
}

// ---------------------------------------------------------------------------
// GEMM small-ws fallback (r3-verified; bias removed).
// ---------------------------------------------------------------------------
__global__ __launch_bounds__(256, 4)
void gemm_fb(const float* __restrict__ X, const float* __restrict__ W1,
             float* __restrict__ H1)
{
    constexpr int K = Dn;
    constexpr int LD = 72;
    __shared__ __align__(16) _Float16 As[2][64][LD];
    __shared__ __align__(16) _Float16 Bs[2][64][LD];

    const int tid = threadIdx.x;
    const int bm = blockIdx.x * 64;
    const int bn = blockIdx.y * 64;
    const int lane = tid & 63;
    const int wid = tid >> 6;
    const int wm = (wid & 1) * 32;
    const int wn = (wid >> 1) * 32;
    const int fr = lane & 15;
    const int fq = lane >> 4;

    const int row0 = tid >> 3;
    const int row1 = (tid + 256) >> 3;
    const int k8_0 = (tid & 7) * 8;

    float4 rx[2][2], rw[2][2];
    const float zero4[4] = {0.f, 0.f, 0.f, 0.f};

    auto load_tiles = [&](int k0) {
        rx[0][0] = *(const float4*)(X + (size_t)(bm + row0) * K + k0 + k8_0);
        rx[0][1] = *(const float4*)(X + (size_t)(bm + row0) * K + k0 + k8_0 + 4);
        rx[1][0] = *(const float4*)(X + (size_t)(bm + row1) * K + k0 + k8_0);
        rx[1][1] = *(const float4*)(X + (size_t)(bm + row1) * K + k0 + k8_0 + 4);
        const int n0 = bn + row0, n1 = bn + row1;
        if (n0 < Hn) {
            rw[0][0] = *(const float4*)(W1 + (size_t)n0 * K + k0 + k8_0);
            rw[0][1] = *(const float4*)(W1 + (size_t)n0 * K + k0 + k8_0 + 4);
        } else { rw[0][0] = *(const float4*)zero4; rw[0][1] = *(const float4*)zero4; }
        if (n1 < Hn) {
            rw[1][0] = *(const float4*)(W1 + (size_t)n1 * K + k0 + k8_0);
            rw[1][1] = *(const float4*)(W1 + (size_t)n1 * K + k0 + k8_0 + 4);
        } else { rw[1][0] = *(const float4*)zero4; rw[1][1] = *(const float4*)zero4; }
    };

    load_tiles(0);
    floatx4 acc0[2][2] = {};
    floatx4 acc1[2][2] = {};

    for (int k0 = 0; k0 < K; k0 += 64) {
#pragma unroll
        for (int p = 0; p < 2; ++p) {
            const int row = p ? row1 : row0;
            float v[8];
            *(float4*)&v[0] = rx[p][0]; *(float4*)&v[4] = rx[p][1];
            half8 hi, lo;
#pragma unroll
            for (int j = 0; j < 8; ++j) {
                hi[j] = (_Float16)v[j];
                lo[j] = (_Float16)((v[j] - (float)hi[j]) * 4096.0f);
            }
            *(half8*)&As[0][row][k8_0] = hi;
            *(half8*)&As[1][row][k8_0] = lo;

            *(float4*)&v[0] = rw[p][0]; *(float4*)&v[4] = rw[p][1];
#pragma unroll
            for (int j = 0; j < 8; ++j) {
                hi[j] = (_Float16)v[j];
                lo[j] = (_Float16)((v[j] - (float)hi[j]) * 4096.0f);
            }
            *(half8*)&Bs[0][row][k8_0] = hi;
            *(half8*)&Bs[1][row][k8_0] = lo;
        }
        __syncthreads();
        if (k0 + 64 < K) load_tiles(k0 + 64);

#pragma unroll
        for (int c = 0; c < 2; ++c) {
            half8 ahi[2], alo[2], bhi[2], blo[2];
#pragma unroll
            for (int mt = 0; mt < 2; ++mt) {
                ahi[mt] = *(const half8*)&As[0][wm + mt * 16 + fr][c * 32 + fq * 8];
                alo[mt] = *(const half8*)&As[1][wm + mt * 16 + fr][c * 32 + fq * 8];
            }
#pragma unroll
            for (int nt = 0; nt < 2; ++nt) {
                bhi[nt] = *(const half8*)&Bs[0][wn + nt * 16 + fr][c * 32 + fq * 8];
                blo[nt] = *(const half8*)&Bs[1][wn + nt * 16 + fr][c * 32 + fq * 8];
            }
#pragma unroll
            for (int mt = 0; mt < 2; ++mt)
#pragma unroll
                for (int nt = 0; nt < 2; ++nt) {
                    acc0[mt][nt] = __builtin_amdgcn_mfma_f32_16x16x32_f16(ahi[mt], bhi[nt], acc0[mt][nt], 0, 0, 0);
                    acc1[mt][nt] = __builtin_amdgcn_mfma_f32_16x16x32_f16(ahi[mt], blo[nt], acc1[mt][nt], 0, 0, 0);
                    acc1[mt][nt] = __builtin_amdgcn_mfma_f32_16x16x32_f16(alo[mt], bhi[nt], acc1[mt][nt], 0, 0, 0);
                }
        }
        __syncthreads();
    }

#pragma unroll
    for (int nt = 0; nt < 2; ++nt) {
        const int n = bn + wn + nt * 16 + fr;
        if (n >= Hn) continue;
#pragma unroll
        for (int mt = 0; mt < 2; ++mt) {
            const int m = bm + wm + mt * 16 + fq * 4;
#pragma unroll
            for (int r = 0; r < 4; ++r)
                H1[(size_t)(m + r) * Hn + n] =
                    acc0[mt][nt][r] + acc1[mt][nt][r] * (1.0f / 4096.0f);
        }
    }
}

// ---------------------------------------------------------------------------
// LIF scan (r4-r8 verified) + bias add + optional split-K partial sum.
// ---------------------------------------------------------------------------
__global__ __launch_bounds__(1024)
void snn_scan(const float* __restrict__ H1, const float* __restrict__ b1,
              const float* __restrict__ W2, const float* __restrict__ b2,
              float* __restrict__ out, int split)
{
    const int b = blockIdx.x;
    const int tid = threadIdx.x;
    const int lane = tid & 63;
    const int wid = tid >> 6;
    const bool act = (tid < Hn);
    constexpr size_t MH = (size_t)Mn * Hn;

    __shared__ float w2s[1024][5];
    __shared__ unsigned smask[1024];
    __shared__ float h2s[Tn][An];

#pragma unroll
    for (int a = 0; a < An; ++a)
        w2s[tid][a] = act ? W2[a * Hn + tid] : 0.f;

    const float b1v = act ? b1[tid] : 0.f;

    float cur[Tn];
#pragma unroll
    for (int t = 0; t < Tn; ++t) {
        const size_t idx = ((size_t)b * Tn + t) * Hn + tid;
        float c = act ? H1[idx] : 0.f;
        if (split && act) c += H1[idx + MH];
        cur[t] = c + b1v;
    }

    unsigned mask = 0;
    float mem1 = 0.f;
#pragma unroll
    for (int t = 0; t < Tn; ++t) {
        const float reset = (mem1 > 1.0f) ? 1.0f : 0.0f;
        mem1 = (0.99f * mem1 + cur[t]) * (1.0f - reset);
        if (mem1 > 1.0f) mask |= (1u << t);
    }
    smask[tid] = act ? mask : 0u;
    __syncthreads();

#pragma unroll
    for (int tt = 0; tt < 2; ++tt) {
        const int t = wid * 2 + tt;
        float p[An] = {0.f, 0.f, 0.f, 0.f};
        for (int h = lane; h < 1024; h += 64) {
            const float g = (smask[h] >> t) & 1u ? 1.0f : 0.0f;
#pragma unroll
            for (int a = 0; a < An; ++a) p[a] += g * w2s[h][a];
        }
#pragma unroll
        for (int off = 32; off > 0; off >>= 1)
#pragma unroll
            for (int a = 0; a < An; ++a) p[a] += __shfl_down(p[a], off, 64);
        if (lane == 0) {
#pragma unroll
            for (int a = 0; a < An; ++a) h2s[t][a] = p[a];
        }
    }
    __syncthreads();

    if (tid < An) {
        const float bias = b2[tid];
        float mem2 = 0.f;
#pragma unroll
        for (int t = 0; t < Tn; ++t) {
            const float h2 = h2s[t][tid] + bias;
            const float reset = (mem2 > 1.0f) ? 1.0f : 0.0f;
            mem2 = (0.99f * mem2 + h2) * (1.0f - reset);
            out[((size_t)b * Tn + t) * An + tid] = (mem2 > 1.0f) ? 1.0f : 0.0f;
        }
    }
}

extern "C" void kernel_launch(void* const* d_in, const int* in_sizes, int n_in,
                              void* d_out, int out_size, void* d_ws, size_t ws_size,
                              hipStream_t stream) {
    const float* x  = (const float*)d_in[0];   // [B,T,D]
    const float* W1 = (const float*)d_in[1];   // [H,D]
    const float* b1 = (const float*)d_in[2];   // [H]
    const float* W2 = (const float*)d_in[3];   // [A,H]
    const float* b2 = (const float*)d_in[4];   // [A]
    float* out = (float*)d_out;                // [B,T,A]

    char* ws = (char*)d_ws;
    float* H1 = (float*)ws;

    if (ws_size >= WS_SPLITK) {
        _Float16* Xh = (_Float16*)(ws + 2 * H1_BYTES);
        _Float16* Xl = (_Float16*)(ws + 2 * H1_BYTES + XS_BYTES);
        _Float16* Wh = (_Float16*)(ws + 2 * H1_BYTES + 2 * XS_BYTES);
        _Float16* Wl = (_Float16*)(ws + 2 * H1_BYTES + 2 * XS_BYTES + WSp_BYTES);

        cvt2<<<256 * 25 + 64 * 25, 256, 0, stream>>>(x, W1, Xh, Xl, Wh, Wl);
        gemm_sk2<<<512, 256, 0, stream>>>(Xh, Xl, Wh, Wl, H1);   // kh=&1, nb=(>>1)&7, mb=>>4
        snn_scan<<<Bn, 1024, 0, stream>>>(H1, b1, W2, b2, out, 1);
    } else if (ws_size >= WS_R7) {
        _Float16* Xh = (_Float16*)(ws + H1_BYTES);
        _Float16* Xl = (_Float16*)(ws + H1_BYTES + XS_BYTES);
        _Float16* Wh = (_Float16*)(ws + H1_BYTES + 2 * XS_BYTES);
        _Float16* Wl = (_Float16*)(ws + H1_BYTES + 2 * XS_BYTES + WSp_BYTES);

        cvt2<<<256 * 25 + 64 * 25, 256, 0, stream>>>(x, W1, Xh, Xl, Wh, Wl);
        gemm_frag2<<<512, 256, 0, stream>>>(Xh, Xl, Wh, Wl, H1);
        snn_scan<<<Bn, 1024, 0, stream>>>(H1, b1, W2, b2, out, 0);
    } else {
        dim3 grid(Mn / 64, (Hn + 63) / 64);
        gemm_fb<<<grid, 256, 0, stream>>>(x, W1, H1);
        snn_scan<<<Bn, 1024, 0, stream>>>(H1, b1, W2, b2, out, 0);
    }
}

// Round 3
// 341.054 us; speedup vs baseline: 1.3117x; 1.3117x over previous
//
#include <hip/hip_runtime.h>
#include <hip/hip_bf16.h>

// Problem constants (fixed by reference setup_inputs)
constexpr int Bn = 128;   // batch
constexpr int Tn = 32;    // timesteps
constexpr int Dn = 6400;  // input dim (K)
constexpr int Hn = 1000;  // hidden  (N)
constexpr int An = 4;     // actions
constexpr int Mn = Bn * Tn;   // 4096 GEMM rows
constexpr int Npad = 1024;    // W rows padded -> no N-guards in GEMM

constexpr int KS = Dn / 32;   // 200 k-chunks of 32
constexpr int MC = Mn / 16;   // 256 m-chunks of 16 rows
constexpr int NC = Npad / 16; // 64  n-chunks of 16 rows

typedef _Float16 half8 __attribute__((ext_vector_type(8)));
typedef _Float16 half4 __attribute__((ext_vector_type(4)));
typedef float floatx4 __attribute__((ext_vector_type(4)));

// Workspace layouts (bytes)
constexpr size_t H1_BYTES  = (size_t)Mn * Hn * 4;       // 16,384,000
constexpr size_t XS_BYTES  = (size_t)Mn * Dn * 2;       // per split
constexpr size_t WSp_BYTES = (size_t)Npad * Dn * 2;     // per split
constexpr size_t WS_R7     = H1_BYTES + 2 * XS_BYTES + 2 * WSp_BYTES;      // 147,456,000
constexpr size_t WS_SPLITK = 2 * H1_BYTES + 2 * XS_BYTES + 2 * WSp_BYTES;  // 163,840,000

__device__ __forceinline__ void async16(const void* g, void* l) {
    __builtin_amdgcn_global_load_lds(
        (const __attribute__((address_space(1))) void*)g,
        (__attribute__((address_space(3))) void*)l, 16, 0, 0);
}

// ---------------------------------------------------------------------------
// Pre-pass (r7/r8-verified): fp16 hi/lo split into fragment-chunk layout,
// both sides 1KB-per-instruction coalesced via LDS transpose.
// ---------------------------------------------------------------------------
__global__ __launch_bounds__(256)
void cvt2(const float* __restrict__ X, const float* __restrict__ W1,
          _Float16* __restrict__ Xh, _Float16* __restrict__ Xl,
          _Float16* __restrict__ Wh, _Float16* __restrict__ Wl)
{
    constexpr int LD2 = 264;
    __shared__ __align__(16) _Float16 hiS[16][LD2];
    __shared__ __align__(16) _Float16 loS[16][LD2];

    const int tid = threadIdx.x;
    const int lane = tid & 63;
    const int w = tid >> 6;
    const int bx = blockIdx.x;

    const float* src;
    _Float16 *dh, *dl;
    int c4, ks0, crow, nrows;
    if (bx < 256 * 25) {                       // X part
        c4 = bx & 255; ks0 = (bx >> 8) * 8;
        src = X; dh = Xh; dl = Xl; crow = MC; nrows = 16;
    } else {                                   // W part (rows >= Hn zeroed)
        const int b2 = bx - 256 * 25;
        c4 = b2 & 63; ks0 = (b2 >> 6) * 8;
        src = W1; dh = Wh; dl = Wl; crow = NC; nrows = Hn - c4 * 16;
    }

#pragma unroll
    for (int j = 0; j < 4; ++j) {
        const int row = w * 4 + j;
        float4 v = make_float4(0.f, 0.f, 0.f, 0.f);
        if (row < nrows)
            v = *(const float4*)(src + (size_t)(c4 * 16 + row) * Dn + ks0 * 32 + lane * 4);
        half4 hi, lo;
        hi[0] = (_Float16)v.x; lo[0] = (_Float16)((v.x - (float)hi[0]) * 4096.0f);
        hi[1] = (_Float16)v.y; lo[1] = (_Float16)((v.y - (float)hi[1]) * 4096.0f);
        hi[2] = (_Float16)v.z; lo[2] = (_Float16)((v.z - (float)hi[2]) * 4096.0f);
        hi[3] = (_Float16)v.w; lo[3] = (_Float16)((v.w - (float)hi[3]) * 4096.0f);
        *(half4*)&hiS[row][lane * 4] = hi;
        *(half4*)&loS[row][lane * 4] = lo;
    }
    __syncthreads();

    const int lr = lane & 15, lg = lane >> 4;
#pragma unroll
    for (int q = 0; q < 2; ++q) {
        const int ks = w * 2 + q;
        const size_t cbase = ((size_t)(ks0 + ks) * crow + c4) * 512;
        const half8 h = *(const half8*)&hiS[lr][ks * 32 + lg * 8];
        const half8 l = *(const half8*)&loS[lr][ks * 32 + lg * 8];
        *(half8*)(dh + cbase + lane * 8) = h;
        *(half8*)(dl + cbase + lane * 8) = l;
    }
}

// ---------------------------------------------------------------------------
// GEMM (primary): 128x128 tile, split-K=2, A via LDS-DMA / B direct-to-reg.
//
// r11 (counted-vmcnt, spill-free). Post-mortem chain:
//  - r8/r9 (~50% MfmaUtil): program order was DMA -> B-loads -> MFMA, so the
//    compiler's register-dependency wait for the LAST B load is vmcnt(0) --
//    draining the just-issued A-DMA every iteration. The prefetch never had
//    cover; each iter stalled ~L2 latency on its own DMA.
//  - r10: tried counted vmcnt + B reg dbuf; 2 live B sets pushed VGPR+AGPR
//    past 256 -> acc spill -> 240 MB scratch writes, memory-bound at 245 us.
// Fix: issue B(it) BEFORE issueA(it+2). Compiler's wait for all B becomes
// vmcnt(4), leaving the DMA in flight across the MFMA block AND the barrier
// (raw s_barrier + manual vmcnt(4), never draining to 0 in the main loop).
// DMA now has ~2 full iterations to land. Single-buffer B (no dbuf) keeps
// VGPR ~100 + 128 AGPR < 256 -> no spill, 2 blocks/CU.
// Correctness: vmcnt is a FIFO counter; each wave's own vmcnt(4) (the 4
// survivors = newest 4 ops = DMA(it+1)) proves its DMA(it) retired before it
// reaches barrier(it); barrier => all waves' DMA(it) landed => buf(it) reads
// safe. Manual vmcnt(4) covers iter 0 (prologue has 8 outstanding).
// DMA(it+2) overwrites buf((it+2)&3), last read two barriers earlier.
// 4-buffer rotation (64 KB LDS; 2 blocks = 128 <= 160 KB), unroll x4 for
// compile-time buffer indices (NIT = 100 = 4*25).
// ---------------------------------------------------------------------------
__global__ __launch_bounds__(256, 2)
void gemm_sk2(const _Float16* __restrict__ Xh, const _Float16* __restrict__ Xl,
              const _Float16* __restrict__ Wh, const _Float16* __restrict__ Wl,
              float* __restrict__ H1)
{
    __shared__ __align__(16) _Float16 S[4][16][512];   // 64 KB: [buf][A chunk hi0-7,lo0-7][1KB]

    const int tid = threadIdx.x;
    const int lane = tid & 63;
    const int w = tid >> 6;
    const int kh = blockIdx.x & 1;
    const int nb = (blockIdx.x >> 1) & 7;
    const int mb = blockIdx.x >> 4;
    const int bm8 = mb * 8;
    const int bn8 = nb * 8;
    const int wm = w & 1;
    const int wn = w >> 1;
    const int ks0 = kh * (KS / 2);
    constexpr int NIT = KS / 2;                // 100 = 4*25

    // A staging: wave w stages hi+lo of m-chunks 2w, 2w+1 (4 async16/wave).
    auto issueA = [&](int ks, int buf) {
        _Float16* base = &S[buf][0][0];
#pragma unroll
        for (int r = 0; r < 2; ++r) {
            const int i = w * 2 + r;
            const size_t ga = ((size_t)(ks * MC + bm8 + i)) * 512 + lane * 8;
            async16(Xh + ga, base + (0 + i) * 512);
            async16(Xl + ga, base + (8 + i) * 512);
        }
    };

    // B fragments: direct global->VGPR, lane-contiguous 1 KB per instruction.
    const _Float16* bhp = Wh + ((size_t)(ks0 * NC + bn8 + wn * 4)) * 512 + lane * 8;
    const _Float16* blp = Wl + ((size_t)(ks0 * NC + bn8 + wn * 4)) * 512 + lane * 8;
    constexpr size_t BSTEP = (size_t)NC * 512;         // per-ks advance (halves)

    floatx4 acc0[4][4] = {};
    floatx4 acc1[4][4] = {};

    // prologue: A-DMA for it=0,1 into buf0,1 (8 vmem ops outstanding)
    issueA(ks0 + 0, 0);
    issueA(ks0 + 1, 1);

    // Body(IT, BUF): [vmcnt(4); s_barrier] -> load B(IT) (8 ops, FIRST) ->
    //                issueA(IT+2) (4 DMA ops, AFTER B) -> ds_read A + MFMA.
#define SK2_BODY(IT, BUF)                                                       \
    {                                                                           \
        asm volatile("s_waitcnt vmcnt(4)" ::: "memory");                        \
        __builtin_amdgcn_sched_barrier(0);                                      \
        __builtin_amdgcn_s_barrier();                                           \
        __builtin_amdgcn_sched_barrier(0);                                      \
        half8 bh[4], bl[4];                                                     \
        {                                                                       \
            const size_t bo = (size_t)(IT) * BSTEP;                             \
            _Pragma("unroll")                                                   \
            for (int nt = 0; nt < 4; ++nt) {                                    \
                bh[nt] = *(const half8*)(bhp + bo + nt * 512);                  \
                bl[nt] = *(const half8*)(blp + bo + nt * 512);                  \
            }                                                                   \
        }                                                                       \
        __builtin_amdgcn_sched_barrier(0);                                      \
        if ((IT) + 2 < NIT) issueA(ks0 + (IT) + 2, ((IT) + 2) & 3);             \
        __builtin_amdgcn_sched_barrier(0);                                      \
        _Pragma("unroll")                                                       \
        for (int mt = 0; mt < 4; ++mt) {                                        \
            const half8 ah = *(const half8*)&S[BUF][wm * 4 + mt][lane * 8];     \
            const half8 al = *(const half8*)&S[BUF][8 + wm * 4 + mt][lane * 8]; \
            _Pragma("unroll")                                                   \
            for (int nt = 0; nt < 4; ++nt) {                                    \
                acc0[mt][nt] = __builtin_amdgcn_mfma_f32_16x16x32_f16(ah, bh[nt], acc0[mt][nt], 0, 0, 0); \
                acc1[mt][nt] = __builtin_amdgcn_mfma_f32_16x16x32_f16(ah, bl[nt], acc1[mt][nt], 0, 0, 0); \
                acc1[mt][nt] = __builtin_amdgcn_mfma_f32_16x16x32_f16(al, bh[nt], acc1[mt][nt], 0, 0, 0); \
            }                                                                   \
        }                                                                       \
    }

    for (int it = 0; it < NIT; it += 4) {
        SK2_BODY(it + 0, 0);
        SK2_BODY(it + 1, 1);
        SK2_BODY(it + 2, 2);
        SK2_BODY(it + 3, 3);
    }
#undef SK2_BODY

    // epilogue (no bias -- scan adds b1): C/D col=lane&15, row=(lane>>4)*4+r
    float* H1o = H1 + (size_t)kh * ((size_t)Mn * Hn);
    const int fr = lane & 15;
    const int fq = lane >> 4;
#pragma unroll
    for (int nt = 0; nt < 4; ++nt) {
        const int n = nb * 128 + wn * 64 + nt * 16 + fr;
        if (n >= Hn) continue;
#pragma unroll
        for (int mt = 0; mt < 4; ++mt) {
            const int m = mb * 128 + wm * 64 + mt * 16 + fq * 4;
#pragma unroll
            for (int r = 0; r < 4; ++r)
                H1o[(size_t)(m + r) * Hn + n] =
                    acc0[mt][nt][r] + acc1[mt][nt][r] * (1.0f / 4096.0f);
        }
    }
}

// ---------------------------------------------------------------------------
// GEMM mid-fallback (r7-verified; bias removed): ws in [147,164) MB.
// ---------------------------------------------------------------------------
constexpr int AH = 0;
constexpr int AL = 8 * 512;
constexpr int BH = 16 * 512;
constexpr int BL = 20 * 512;
constexpr int BUFSZ = 24 * 512;

__global__ __launch_bounds__(256, 2)
void gemm_frag2(const _Float16* __restrict__ Xh, const _Float16* __restrict__ Xl,
                const _Float16* __restrict__ Wh, const _Float16* __restrict__ Wl,
                float* __restrict__ H1)
{
    __shared__ __align__(16) _Float16 S[2 * BUFSZ];

    const int tid = threadIdx.x;
    const int lane = tid & 63;
    const int w = tid >> 6;
    const int nb = blockIdx.x & 15;
    const int mb = blockIdx.x >> 4;
    const int bm4 = mb * 8;
    const int bn4 = nb * 4;
    const int wm = w & 1;
    const int wn = w >> 1;

    auto issue = [&](int ks, int buf) {
        _Float16* base = &S[buf * BUFSZ];
#pragma unroll
        for (int r = 0; r < 2; ++r) {
            const int i = w * 2 + r;
            const size_t ga = ((size_t)(ks * MC + bm4 + i)) * 512 + lane * 8;
            async16(Xh + ga, base + AH + i * 512);
            async16(Xl + ga, base + AL + i * 512);
        }
        const size_t gb = ((size_t)(ks * NC + bn4 + w)) * 512 + lane * 8;
        async16(Wh + gb, base + BH + w * 512);
        async16(Wl + gb, base + BL + w * 512);
    };

    floatx4 acc0[4][2] = {};
    floatx4 acc1[4][2] = {};

    issue(0, 0);
    for (int it = 0; it < KS; ++it) {
        const int buf = it & 1;
        __syncthreads();
        if (it + 1 < KS) issue(it + 1, buf ^ 1);

        const _Float16* base = &S[buf * BUFSZ];
        half8 ah[4], al[4], bh[2], bl[2];
#pragma unroll
        for (int mt = 0; mt < 4; ++mt) {
            ah[mt] = *(const half8*)(base + AH + (wm * 4 + mt) * 512 + lane * 8);
            al[mt] = *(const half8*)(base + AL + (wm * 4 + mt) * 512 + lane * 8);
        }
#pragma unroll
        for (int nt = 0; nt < 2; ++nt) {
            bh[nt] = *(const half8*)(base + BH + (wn * 2 + nt) * 512 + lane * 8);
            bl[nt] = *(const half8*)(base + BL + (wn * 2 + nt) * 512 + lane * 8);
        }
#pragma unroll
        for (int mt = 0; mt < 4; ++mt)
#pragma unroll
            for (int nt = 0; nt < 2; ++nt) {
                acc0[mt][nt] = __builtin_amdgcn_mfma_f32_16x16x32_f16(ah[mt], bh[nt], acc0[mt][nt], 0, 0, 0);
                acc1[mt][nt] = __builtin_amdgcn_mfma_f32_16x16x32_f16(ah[mt], bl[nt], acc1[mt][nt], 0, 0, 0);
                acc1[mt][nt] = __builtin_amdgcn_mfma_f32_16x16x32_f16(al[mt], bh[nt], acc1[mt][nt], 0, 0, 0);
            }
    }

    const int fr = lane & 15;
    const int fq = lane >> 4;
#pragma unroll
    for (int nt = 0; nt < 2; ++nt) {
        const int n = nb * 64 + wn * 32 + nt * 16 + fr;
        if (n >= Hn) continue;
#pragma unroll
        for (int mt = 0; mt < 4; ++mt) {
            const int m = mb * 128 + wm * 64 + mt * 16 + fq * 4;
#pragma unroll
            for (int r = 0; r < 4; ++r)
                H1[(size_t)(m + r) * Hn + n] =
                    acc0[mt][nt][r] + acc1[mt][nt][r] * (1.0f / 4096.0f);
        }
    }
}

// ---------------------------------------------------------------------------
// GEMM small-ws fallback (r3-verified; bias removed).
// ---------------------------------------------------------------------------
__global__ __launch_bounds__(256, 4)
void gemm_fb(const float* __restrict__ X, const float* __restrict__ W1,
             float* __restrict__ H1)
{
    constexpr int K = Dn;
    constexpr int LD = 72;
    __shared__ __align__(16) _Float16 As[2][64][LD];
    __shared__ __align__(16) _Float16 Bs[2][64][LD];

    const int tid = threadIdx.x;
    const int bm = blockIdx.x * 64;
    const int bn = blockIdx.y * 64;
    const int lane = tid & 63;
    const int wid = tid >> 6;
    const int wm = (wid & 1) * 32;
    const int wn = (wid >> 1) * 32;
    const int fr = lane & 15;
    const int fq = lane >> 4;

    const int row0 = tid >> 3;
    const int row1 = (tid + 256) >> 3;
    const int k8_0 = (tid & 7) * 8;

    float4 rx[2][2], rw[2][2];
    const float zero4[4] = {0.f, 0.f, 0.f, 0.f};

    auto load_tiles = [&](int k0) {
        rx[0][0] = *(const float4*)(X + (size_t)(bm + row0) * K + k0 + k8_0);
        rx[0][1] = *(const float4*)(X + (size_t)(bm + row0) * K + k0 + k8_0 + 4);
        rx[1][0] = *(const float4*)(X + (size_t)(bm + row1) * K + k0 + k8_0);
        rx[1][1] = *(const float4*)(X + (size_t)(bm + row1) * K + k0 + k8_0 + 4);
        const int n0 = bn + row0, n1 = bn + row1;
        if (n0 < Hn) {
            rw[0][0] = *(const float4*)(W1 + (size_t)n0 * K + k0 + k8_0);
            rw[0][1] = *(const float4*)(W1 + (size_t)n0 * K + k0 + k8_0 + 4);
        } else { rw[0][0] = *(const float4*)zero4; rw[0][1] = *(const float4*)zero4; }
        if (n1 < Hn) {
            rw[1][0] = *(const float4*)(W1 + (size_t)n1 * K + k0 + k8_0);
            rw[1][1] = *(const float4*)(W1 + (size_t)n1 * K + k0 + k8_0 + 4);
        } else { rw[1][0] = *(const float4*)zero4; rw[1][1] = *(const float4*)zero4; }
    };

    load_tiles(0);
    floatx4 acc0[2][2] = {};
    floatx4 acc1[2][2] = {};

    for (int k0 = 0; k0 < K; k0 += 64) {
#pragma unroll
        for (int p = 0; p < 2; ++p) {
            const int row = p ? row1 : row0;
            float v[8];
            *(float4*)&v[0] = rx[p][0]; *(float4*)&v[4] = rx[p][1];
            half8 hi, lo;
#pragma unroll
            for (int j = 0; j < 8; ++j) {
                hi[j] = (_Float16)v[j];
                lo[j] = (_Float16)((v[j] - (float)hi[j]) * 4096.0f);
            }
            *(half8*)&As[0][row][k8_0] = hi;
            *(half8*)&As[1][row][k8_0] = lo;

            *(float4*)&v[0] = rw[p][0]; *(float4*)&v[4] = rw[p][1];
#pragma unroll
            for (int j = 0; j < 8; ++j) {
                hi[j] = (_Float16)v[j];
                lo[j] = (_Float16)((v[j] - (float)hi[j]) * 4096.0f);
            }
            *(half8*)&Bs[0][row][k8_0] = hi;
            *(half8*)&Bs[1][row][k8_0] = lo;
        }
        __syncthreads();
        if (k0 + 64 < K) load_tiles(k0 + 64);

#pragma unroll
        for (int c = 0; c < 2; ++c) {
            half8 ahi[2], alo[2], bhi[2], blo[2];
#pragma unroll
            for (int mt = 0; mt < 2; ++mt) {
                ahi[mt] = *(const half8*)&As[0][wm + mt * 16 + fr][c * 32 + fq * 8];
                alo[mt] = *(const half8*)&As[1][wm + mt * 16 + fr][c * 32 + fq * 8];
            }
#pragma unroll
            for (int nt = 0; nt < 2; ++nt) {
                bhi[nt] = *(const half8*)&Bs[0][wn + nt * 16 + fr][c * 32 + fq * 8];
                blo[nt] = *(const half8*)&Bs[1][wn + nt * 16 + fr][c * 32 + fq * 8];
            }
#pragma unroll
            for (int mt = 0; mt < 2; ++mt)
#pragma unroll
                for (int nt = 0; nt < 2; ++nt) {
                    acc0[mt][nt] = __builtin_amdgcn_mfma_f32_16x16x32_f16(ahi[mt], bhi[nt], acc0[mt][nt], 0, 0, 0);
                    acc1[mt][nt] = __builtin_amdgcn_mfma_f32_16x16x32_f16(ahi[mt], blo[nt], acc1[mt][nt], 0, 0, 0);
                    acc1[mt][nt] = __builtin_amdgcn_mfma_f32_16x16x32_f16(alo[mt], bhi[nt], acc1[mt][nt], 0, 0, 0);
                }
        }
        __syncthreads();
    }

#pragma unroll
    for (int nt = 0; nt < 2; ++nt) {
        const int n = bn + wn + nt * 16 + fr;
        if (n >= Hn) continue;
#pragma unroll
        for (int mt = 0; mt < 2; ++mt) {
            const int m = bm + wm + mt * 16 + fq * 4;
#pragma unroll
            for (int r = 0; r < 4; ++r)
                H1[(size_t)(m + r) * Hn + n] =
                    acc0[mt][nt][r] + acc1[mt][nt][r] * (1.0f / 4096.0f);
        }
    }
}

// ---------------------------------------------------------------------------
// LIF scan (r4-r8 verified) + bias add + optional split-K partial sum.
// ---------------------------------------------------------------------------
__global__ __launch_bounds__(1024)
void snn_scan(const float* __restrict__ H1, const float* __restrict__ b1,
              const float* __restrict__ W2, const float* __restrict__ b2,
              float* __restrict__ out, int split)
{
    const int b = blockIdx.x;
    const int tid = threadIdx.x;
    const int lane = tid & 63;
    const int wid = tid >> 6;
    const bool act = (tid < Hn);
    constexpr size_t MH = (size_t)Mn * Hn;

    __shared__ float w2s[1024][5];
    __shared__ unsigned smask[1024];
    __shared__ float h2s[Tn][An];

#pragma unroll
    for (int a = 0; a < An; ++a)
        w2s[tid][a] = act ? W2[a * Hn + tid] : 0.f;

    const float b1v = act ? b1[tid] : 0.f;

    float cur[Tn];
#pragma unroll
    for (int t = 0; t < Tn; ++t) {
        const size_t idx = ((size_t)b * Tn + t) * Hn + tid;
        float c = act ? H1[idx] : 0.f;
        if (split && act) c += H1[idx + MH];
        cur[t] = c + b1v;
    }

    unsigned mask = 0;
    float mem1 = 0.f;
#pragma unroll
    for (int t = 0; t < Tn; ++t) {
        const float reset = (mem1 > 1.0f) ? 1.0f : 0.0f;
        mem1 = (0.99f * mem1 + cur[t]) * (1.0f - reset);
        if (mem1 > 1.0f) mask |= (1u << t);
    }
    smask[tid] = act ? mask : 0u;
    __syncthreads();

#pragma unroll
    for (int tt = 0; tt < 2; ++tt) {
        const int t = wid * 2 + tt;
        float p[An] = {0.f, 0.f, 0.f, 0.f};
        for (int h = lane; h < 1024; h += 64) {
            const float g = (smask[h] >> t) & 1u ? 1.0f : 0.0f;
#pragma unroll
            for (int a = 0; a < An; ++a) p[a] += g * w2s[h][a];
        }
#pragma unroll
        for (int off = 32; off > 0; off >>= 1)
#pragma unroll
            for (int a = 0; a < An; ++a) p[a] += __shfl_down(p[a], off, 64);
        if (lane == 0) {
#pragma unroll
            for (int a = 0; a < An; ++a) h2s[t][a] = p[a];
        }
    }
    __syncthreads();

    if (tid < An) {
        const float bias = b2[tid];
        float mem2 = 0.f;
#pragma unroll
        for (int t = 0; t < Tn; ++t) {
            const float h2 = h2s[t][tid] + bias;
            const float reset = (mem2 > 1.0f) ? 1.0f : 0.0f;
            mem2 = (0.99f * mem2 + h2) * (1.0f - reset);
            out[((size_t)b * Tn + t) * An + tid] = (mem2 > 1.0f) ? 1.0f : 0.0f;
        }
    }
}

extern "C" void kernel_launch(void* const* d_in, const int* in_sizes, int n_in,
                              void* d_out, int out_size, void* d_ws, size_t ws_size,
                              hipStream_t stream) {
    const float* x  = (const float*)d_in[0];   // [B,T,D]
    const float* W1 = (const float*)d_in[1];   // [H,D]
    const float* b1 = (const float*)d_in[2];   // [H]
    const float* W2 = (const float*)d_in[3];   // [A,H]
    const float* b2 = (const float*)d_in[4];   // [A]
    float* out = (float*)d_out;                // [B,T,A]

    char* ws = (char*)d_ws;
    float* H1 = (float*)ws;

    if (ws_size >= WS_SPLITK) {
        _Float16* Xh = (_Float16*)(ws + 2 * H1_BYTES);
        _Float16* Xl = (_Float16*)(ws + 2 * H1_BYTES + XS_BYTES);
        _Float16* Wh = (_Float16*)(ws + 2 * H1_BYTES + 2 * XS_BYTES);
        _Float16* Wl = (_Float16*)(ws + 2 * H1_BYTES + 2 * XS_BYTES + WSp_BYTES);

        cvt2<<<256 * 25 + 64 * 25, 256, 0, stream>>>(x, W1, Xh, Xl, Wh, Wl);
        gemm_sk2<<<512, 256, 0, stream>>>(Xh, Xl, Wh, Wl, H1);   // kh=&1, nb=(>>1)&7, mb=>>4
        snn_scan<<<Bn, 1024, 0, stream>>>(H1, b1, W2, b2, out, 1);
    } else if (ws_size >= WS_R7) {
        _Float16* Xh = (_Float16*)(ws + H1_BYTES);
        _Float16* Xl = (_Float16*)(ws + H1_BYTES + XS_BYTES);
        _Float16* Wh = (_Float16*)(ws + H1_BYTES + 2 * XS_BYTES);
        _Float16* Wl = (_Float16*)(ws + H1_BYTES + 2 * XS_BYTES + WSp_BYTES);

        cvt2<<<256 * 25 + 64 * 25, 256, 0, stream>>>(x, W1, Xh, Xl, Wh, Wl);
        gemm_frag2<<<512, 256, 0, stream>>>(Xh, Xl, Wh, Wl, H1);
        snn_scan<<<Bn, 1024, 0, stream>>>(H1, b1, W2, b2, out, 0);
    } else {
        dim3 grid(Mn / 64, (Hn + 63) / 64);
        gemm_fb<<<grid, 256, 0, stream>>>(x, W1, H1);
        snn_scan<<<Bn, 1024, 0, stream>>>(H1, b1, W2, b2, out, 0);
    }
}